// Round 8
// baseline (310.715 us; speedup 1.0000x reference)
//
#include <hip/hip_runtime.h>

// ---- bucket-sort CSR parameters (n <= 131072, so src/dst fit in 17 bits) ----
#define NPB_SHIFT 7
#define NPB       128      // nodes per bucket
#define CHUNK     4096     // edges per hist/scatter block (16 per thread)
#define STAGE_CAP 8192     // bucket_build LDS staging (ints); avg bucket ~4092
#define NBKT_MAX  1024     // LDS bin cap (needs nbkt <= 1024)

// ---------------- pass 1: per-block LDS histogram of dst buckets ----------------

__global__ void hist_kernel(const int* __restrict__ dst, int* __restrict__ hist,
                            int E, int HBr, int nbkt) {
    __shared__ int bins[NBKT_MAX];
    int tid = threadIdx.x;
    for (int i = tid; i < nbkt; i += 256) bins[i] = 0;
    __syncthreads();
    int start = blockIdx.x * CHUNK;
    #pragma unroll
    for (int j = 0; j < 16; ++j) {
        int e = start + j * 256 + tid;
        if (e < E) atomicAdd(&bins[dst[e] >> NPB_SHIFT], 1);
    }
    __syncthreads();
    for (int i = tid; i < nbkt; i += 256)
        hist[(size_t)i * HBr + blockIdx.x] = bins[i];
}

// ---------------- 3-phase exclusive scan over hist matrix (in place) ----------------

__global__ void scan_block8_kernel(int* data, int* __restrict__ partial, int len) {
    __shared__ int wtot[16];
    int tid = threadIdx.x, lane = tid & 63, wid = tid >> 6;
    int base = blockIdx.x * 8192 + tid * 8;
    int v[8]; int s = 0;
    #pragma unroll
    for (int j = 0; j < 8; ++j) {
        int i = base + j;
        v[j] = (i < len) ? data[i] : 0;
        s += v[j];
    }
    int inc = s;
    #pragma unroll
    for (int o = 1; o < 64; o <<= 1) { int t = __shfl_up(inc, o); if (lane >= o) inc += t; }
    if (lane == 63) wtot[wid] = inc;
    __syncthreads();
    if (tid == 0) {
        int run = 0;
        #pragma unroll
        for (int w = 0; w < 16; ++w) { int t = wtot[w]; wtot[w] = run; run += t; }
        partial[blockIdx.x] = run;
    }
    __syncthreads();
    int excl = wtot[wid] + inc - s;
    #pragma unroll
    for (int j = 0; j < 8; ++j) {
        int i = base + j;
        if (i < len) data[i] = excl;
        excl += v[j];
    }
}

__global__ void scan_partials_kernel(int* partial, int nb) {
    int t = threadIdx.x;  // 64 threads; nb <= 128
    int i0 = 2 * t, i1 = 2 * t + 1;
    int v0 = (i0 < nb) ? partial[i0] : 0;
    int v1 = (i1 < nb) ? partial[i1] : 0;
    int s = v0 + v1;
    int inc = s;
    #pragma unroll
    for (int o = 1; o < 64; o <<= 1) { int u = __shfl_up(inc, o); if (t >= o) inc += u; }
    int excl = inc - s;
    if (i0 < nb) partial[i0] = excl;
    if (i1 < nb) partial[i1] = excl + v0;
}

__global__ void add_base_kernel(int* data, const int* __restrict__ partial, int len) {
    int i = blockIdx.x * blockDim.x + threadIdx.x;
    if (i < len) data[i] += partial[i >> 13];
}

// ---------------- pass 2: tile-sort scatter into bucket-ordered ebuf ----------------
// payload packed: (dst & 127) << 17 | src   (src < 2^17)

__global__ void scatter_kernel(const int* __restrict__ src, const int* __restrict__ dst,
                               const int* __restrict__ offset, int* __restrict__ ebuf,
                               int E, int HBr, int nbkt) {
    __shared__ int gbase[NBKT_MAX];
    __shared__ int thist[NBKT_MAX];
    __shared__ int toff[NBKT_MAX + 1];
    __shared__ int stage[CHUNK];
    __shared__ unsigned short bstage[CHUNK];
    __shared__ int wtot4[4];
    int tid = threadIdx.x, lane = tid & 63, wid = tid >> 6;
    for (int i = tid; i < nbkt; i += 256) gbase[i] = offset[(size_t)i * HBr + blockIdx.x];
    for (int i = tid; i < NBKT_MAX; i += 256) thist[i] = 0;
    __syncthreads();
    int start = blockIdx.x * CHUNK;
    int s_[16], d_[16], r_[16];
    #pragma unroll
    for (int j = 0; j < 16; ++j) {
        int e = start + j * 256 + tid;
        if (e < E) {
            s_[j] = src[e];
            d_[j] = dst[e];
            r_[j] = atomicAdd(&thist[d_[j] >> NPB_SHIFT], 1);
        } else {
            d_[j] = -1;
        }
    }
    __syncthreads();
    int a0 = thist[4 * tid], a1 = thist[4 * tid + 1],
        a2 = thist[4 * tid + 2], a3 = thist[4 * tid + 3];
    int ss = a0 + a1 + a2 + a3;
    int inc = ss;
    #pragma unroll
    for (int o = 1; o < 64; o <<= 1) { int t = __shfl_up(inc, o); if (lane >= o) inc += t; }
    if (lane == 63) wtot4[wid] = inc;
    __syncthreads();
    int wbase = 0;
    for (int w = 0; w < wid; ++w) wbase += wtot4[w];
    int excl = wbase + inc - ss;
    toff[4 * tid]     = excl;
    toff[4 * tid + 1] = excl + a0;
    toff[4 * tid + 2] = excl + a0 + a1;
    toff[4 * tid + 3] = excl + a0 + a1 + a2;
    if (tid == 255) toff[1024] = excl + ss;  // total valid
    __syncthreads();
    #pragma unroll
    for (int j = 0; j < 16; ++j) {
        if (d_[j] >= 0) {
            int b = d_[j] >> NPB_SHIFT;
            int q = toff[b] + r_[j];
            stage[q]  = ((d_[j] & (NPB - 1)) << 17) | s_[j];
            bstage[q] = (unsigned short)b;
        }
    }
    __syncthreads();
    int total = toff[1024];
    for (int j = tid; j < total; j += 256) {
        int b = bstage[j];
        ebuf[gbase[b] + (j - toff[b])] = stage[j];
    }
}

// ---------------- pass 3: per-bucket CSR build + row_start + dinv ----------------

__global__ void bucket_build_kernel(const int* __restrict__ ebuf, const int* __restrict__ offset,
                                    int* __restrict__ csr_src, int* __restrict__ row_start,
                                    float* __restrict__ dinv, int E, int HBr, int nbkt, int n) {
    __shared__ int cnt[NPB], cur[NPB];
    __shared__ int stage[STAGE_CAP];
    __shared__ int wtot2[2];
    int tid = threadIdx.x;
    int k = blockIdx.x;
    int bb = offset[(size_t)k * HBr];
    int be = (k + 1 < nbkt) ? offset[(size_t)(k + 1) * HBr] : E;
    int bsize = be - bb;
    if (tid < NPB) cnt[tid] = 0;
    __syncthreads();
    for (int e = bb + tid; e < be; e += 256) atomicAdd(&cnt[ebuf[e] >> 17], 1);
    __syncthreads();
    int lane = tid & 63, wid = tid >> 6;
    int c = 0, inc = 0;
    if (tid < NPB) {
        c = cnt[tid];
        inc = c;
        #pragma unroll
        for (int o = 1; o < 64; o <<= 1) { int t = __shfl_up(inc, o); if (lane >= o) inc += t; }
        if (lane == 63) wtot2[wid] = inc;
    }
    __syncthreads();
    if (tid < NPB) {
        int base = (wid == 1) ? wtot2[0] : 0;
        int excl = base + inc - c;
        cur[tid] = excl;
        int node = k * NPB + tid;
        if (node < n) {
            row_start[node] = bb + excl;
            dinv[node] = rsqrtf((float)(c + 1));  // self-loop
        }
    }
    if (k == 0 && tid == 0) row_start[n] = E;
    __syncthreads();
    if (bsize <= STAGE_CAP) {
        for (int e = bb + tid; e < be; e += 256) {
            int v = ebuf[e];
            int r = atomicAdd(&cur[v >> 17], 1);
            stage[r] = v & 0x1FFFF;
        }
        __syncthreads();
        for (int j = tid; j < bsize; j += 256) csr_src[bb + j] = stage[j];  // coalesced
    } else {
        for (int e = bb + tid; e < be; e += 256) {
            int v = ebuf[e];
            int r = atomicAdd(&cur[v >> 17], 1);
            csr_src[bb + r] = v & 0x1FFFF;
        }
    }
}

// ---------------- pad + scale: g0[i][k] = (k<11) ? x[i][k]*dinv[i] : 0  (16-wide) ------------

__global__ void pad_scale_kernel(const float* __restrict__ x, const float* __restrict__ dinv,
                                 float* __restrict__ g, int n) {
    int i = blockIdx.x * blockDim.x + threadIdx.x;
    if (i >= n) return;
    float s = dinv[i];
    float v[16];
    #pragma unroll
    for (int k = 0; k < 11; ++k) v[k] = x[i * 11 + k] * s;
    #pragma unroll
    for (int k = 11; k < 16; ++k) v[k] = 0.f;
    #pragma unroll
    for (int k = 0; k < 16; ++k) g[i * 16 + k] = v[k];
}

// ---------------- fused gather-aggregate + parallel register-epilogue linear ----------------
// pre = dinv[d] * (sum_{s in N(d)} g[s] + g[d])        (g rows carry dinv[s])
// out[d] = [relu](pre @ W + b) [* dinv[d]]             (scale preps next layer's g)
// One wave per node, 8 lanes per row (q = lane&7 picks the VW-float chunk).
// Epilogue: lane (q,grp) holds features q*VW..; loads its private W slice
// wreg[c][k] = W[q*VW+c][JPL*grp+k] AFTER the gather (keeps gather reg-pressure low),
// computes JPL independent partial dots, butterflies over q (3 stages), stores.

template <int FIN, int FINR, int FOUT, bool RELU, bool SCALE>
__global__ void fused_agg_linear_kernel(const float* __restrict__ g,
                                        const int* __restrict__ row_start,
                                        const int* __restrict__ csr_src,
                                        const float* __restrict__ dinv,
                                        const float* __restrict__ W,
                                        const float* __restrict__ bias,
                                        float* __restrict__ out, int n) {
    constexpr int VW  = FIN / 8;   // floats per lane chunk (2 or 4)
    constexpr int JPL = FOUT / 8;  // outputs per lane (2, 4, or 8)
    int lane = threadIdx.x & 63;
    int wid  = threadIdx.x >> 6;
    int node = blockIdx.x * (blockDim.x >> 6) + wid;
    if (node >= n) return;
    int q   = lane & 7;        // chunk index within row
    int grp = lane >> 3;       // row slot within each 8-row batch / output group
    int beg = row_start[node];
    int end = row_start[node + 1];
    float acc[VW];
    #pragma unroll
    for (int c = 0; c < VW; ++c) acc[c] = 0.f;

    for (int p = beg; p < end; p += 64) {
        int nrem = end - p;                               // wave-uniform
        int idx  = csr_src[min(p + lane, end - 1)];       // coalesced, always in-bounds
        int   s[8];
        float m[8];
        #pragma unroll
        for (int u = 0; u < 8; ++u) {
            int slot  = u * 8 + grp;
            bool val  = slot < nrem;
            int  raw  = __shfl(idx, slot);
            s[u] = val ? raw : node;                      // clamp to self row (cached)
            m[u] = val ? 1.f : 0.f;
        }
        if constexpr (VW == 2) {
            const float2* gv = reinterpret_cast<const float2*>(g);
            float2 v[8];
            #pragma unroll
            for (int u = 0; u < 8; ++u) v[u] = gv[(size_t)s[u] * 8 + q];
            #pragma unroll
            for (int u = 0; u < 8; ++u) {
                acc[0] = fmaf(m[u], v[u].x, acc[0]);
                acc[1] = fmaf(m[u], v[u].y, acc[1]);
            }
        } else {
            const float4* gv = reinterpret_cast<const float4*>(g);
            float4 v[8];
            #pragma unroll
            for (int u = 0; u < 8; ++u) v[u] = gv[(size_t)s[u] * 8 + q];
            #pragma unroll
            for (int u = 0; u < 8; ++u) {
                acc[0] = fmaf(m[u], v[u].x, acc[0]);
                acc[1] = fmaf(m[u], v[u].y, acc[1]);
                acc[2] = fmaf(m[u], v[u].z, acc[2]);
                acc[3] = fmaf(m[u], v[u].w, acc[3]);
            }
        }
    }

    // butterfly-reduce across the 8 row-groups (lanes sharing q end with chunk totals)
    #pragma unroll
    for (int off = 8; off < 64; off <<= 1)
        #pragma unroll
        for (int c = 0; c < VW; ++c) acc[c] += __shfl_xor(acc[c], off);

    // add self row, apply dinv[d]
    float dn = dinv[node];
    {
        if constexpr (VW == 2) {
            float2 v = reinterpret_cast<const float2*>(g)[(size_t)node * 8 + q];
            acc[0] += v.x; acc[1] += v.y;
        } else {
            float4 v = reinterpret_cast<const float4*>(g)[(size_t)node * 8 + q];
            acc[0] += v.x; acc[1] += v.y; acc[2] += v.z; acc[3] += v.w;
        }
        #pragma unroll
        for (int c = 0; c < VW; ++c) acc[c] *= dn;
    }

    // per-lane W slice (loaded after gather: off the gather's register peak; L1-hot)
    float wreg[VW][JPL], breg[JPL];
    #pragma unroll
    for (int c = 0; c < VW; ++c) {
        int f = q * VW + c;
        #pragma unroll
        for (int k = 0; k < JPL; ++k)
            wreg[c][k] = (f < FINR) ? W[f * FOUT + JPL * grp + k] : 0.f;
    }
    #pragma unroll
    for (int k = 0; k < JPL; ++k) breg[k] = bias[JPL * grp + k];

    // JPL independent partial dots over this lane's VW features
    float pj[JPL];
    #pragma unroll
    for (int k = 0; k < JPL; ++k) {
        float s = 0.f;
        #pragma unroll
        for (int c = 0; c < VW; ++c) s = fmaf(acc[c], wreg[c][k], s);
        pj[k] = s;
    }
    // butterfly over q (3 stages, JPL values pipelined) -> full dots for j = JPL*grp+k
    #pragma unroll
    for (int off = 1; off < 8; off <<= 1)
        #pragma unroll
        for (int k = 0; k < JPL; ++k) pj[k] += __shfl_xor(pj[k], off);
    #pragma unroll
    for (int k = 0; k < JPL; ++k) {
        float o = pj[k] + breg[k];
        if (RELU) o = fmaxf(o, 0.f);
        if (SCALE) o *= dn;
        pj[k] = o;
    }
    if (q < JPL) {
        float o = pj[0];
        #pragma unroll
        for (int k = 1; k < JPL; ++k) o = (q == k) ? pj[k] : o;  // static-index select
        out[(size_t)node * FOUT + JPL * grp + q] = o;
    }
}

// ---------------- launch ----------------

extern "C" void kernel_launch(void* const* d_in, const int* in_sizes, int n_in,
                              void* d_out, int out_size, void* d_ws, size_t ws_size,
                              hipStream_t stream) {
    const float* x  = (const float*)d_in[0];
    const int*   ei = (const int*)d_in[1];
    const float* W1 = (const float*)d_in[2];
    const float* b1 = (const float*)d_in[3];
    const float* W2 = (const float*)d_in[4];
    const float* b2 = (const float*)d_in[5];
    const float* W3 = (const float*)d_in[6];
    const float* b3 = (const float*)d_in[7];
    float* out = (float*)d_out;

    const int n = in_sizes[0] / 11;   // 100000
    const int E = in_sizes[1] / 2;    // 3200000
    const int* src = ei;
    const int* dst = ei + E;

    const int nbkt = (n + NPB - 1) >> NPB_SHIFT;        // 782
    const int HBr  = (E + CHUNK - 1) / CHUNK;           // 782
    const size_t len = (size_t)nbkt * HBr;              // 611,524
    const int nb = (int)((len + 8191) / 8192);          // 75 (<=128)

    char* ws = (char*)d_ws;
    size_t off = 0;
    auto alloc = [&](size_t bytes) {
        void* p = ws + off;
        off = (off + bytes + 255) & ~(size_t)255;
        return p;
    };
    int*   offbuf    = (int*)  alloc(len * 4);
    int*   partial   = (int*)  alloc((size_t)128 * 4);
    int*   ebuf      = (int*)  alloc((size_t)E * 4);
    int*   csr_src   = (int*)  alloc((size_t)E * 4);
    int*   row_start = (int*)  alloc((size_t)(n + 1) * 4);
    float* dinv      = (float*)alloc((size_t)n * 4);
    float* g0        = (float*)alloc((size_t)n * 16 * 4);
    float* g1        = (float*)alloc((size_t)n * 16 * 4);
    float* g2        = (float*)alloc((size_t)n * 32 * 4);
    (void)ws_size;

    const int B = 256;
    int gn   = (n + B - 1) / B;
    int glen = (int)((len + B - 1) / B);
    int gagg = (n + 3) / 4;           // one wave per node

    // ---- atomic-free CSR build ----
    hist_kernel<<<HBr, B, 0, stream>>>(dst, offbuf, E, HBr, nbkt);
    scan_block8_kernel<<<nb, 1024, 0, stream>>>(offbuf, partial, (int)len);
    scan_partials_kernel<<<1, 64, 0, stream>>>(partial, nb);
    add_base_kernel<<<glen, B, 0, stream>>>(offbuf, partial, (int)len);
    scatter_kernel<<<HBr, B, 0, stream>>>(src, dst, offbuf, ebuf, E, HBr, nbkt);
    bucket_build_kernel<<<nbkt, B, 0, stream>>>(ebuf, offbuf, csr_src, row_start, dinv, E, HBr, nbkt, n);

    // ---- g0 = pad16(x) * dinv ----
    pad_scale_kernel<<<gn, B, 0, stream>>>(x, dinv, g0, n);

    // layer 1: agg(16-wide, 11 real) + 11->16 linear + relu, scaled for next layer
    fused_agg_linear_kernel<16, 11, 16, true, true>
        <<<gagg, B, 0, stream>>>(g0, row_start, csr_src, dinv, W1, b1, g1, n);

    // layer 2: agg(16) + 16->32 linear + relu, scaled
    fused_agg_linear_kernel<16, 16, 32, true, true>
        <<<gagg, B, 0, stream>>>(g1, row_start, csr_src, dinv, W2, b2, g2, n);

    // layer 3: agg(32) + 32->64 linear + bias, no relu, no scale
    fused_agg_linear_kernel<32, 32, 64, false, false>
        <<<gagg, B, 0, stream>>>(g2, row_start, csr_src, dinv, W3, b3, out, n);
}

// Round 9
// 239.358 us; speedup vs baseline: 1.2981x; 1.2981x over previous
//
#include <hip/hip_runtime.h>

// ---- bucket-sort CSR parameters (n <= 131072, so src/dst fit in 17 bits) ----
#define NPB_SHIFT 7
#define NPB       128      // nodes per bucket
#define CHUNK     4096     // edges per hist/scatter block (16 per thread)
#define STAGE_CAP 8192     // bucket_build LDS staging (ints); avg bucket ~4092
#define NBKT_MAX  1024     // LDS bin cap (needs nbkt <= 1024)

// ---------------- pass 1: per-block LDS histogram of dst buckets ----------------

__global__ void hist_kernel(const int* __restrict__ dst, int* __restrict__ hist,
                            int E, int HBr, int nbkt) {
    __shared__ int bins[NBKT_MAX];
    int tid = threadIdx.x;
    for (int i = tid; i < nbkt; i += 256) bins[i] = 0;
    __syncthreads();
    int start = blockIdx.x * CHUNK;
    #pragma unroll
    for (int j = 0; j < 16; ++j) {
        int e = start + j * 256 + tid;
        if (e < E) atomicAdd(&bins[dst[e] >> NPB_SHIFT], 1);
    }
    __syncthreads();
    for (int i = tid; i < nbkt; i += 256)
        hist[(size_t)i * HBr + blockIdx.x] = bins[i];
}

// ---------------- 3-phase exclusive scan over hist matrix (in place) ----------------

__global__ void scan_block8_kernel(int* data, int* __restrict__ partial, int len) {
    __shared__ int wtot[16];
    int tid = threadIdx.x, lane = tid & 63, wid = tid >> 6;
    int base = blockIdx.x * 8192 + tid * 8;
    int v[8]; int s = 0;
    #pragma unroll
    for (int j = 0; j < 8; ++j) {
        int i = base + j;
        v[j] = (i < len) ? data[i] : 0;
        s += v[j];
    }
    int inc = s;
    #pragma unroll
    for (int o = 1; o < 64; o <<= 1) { int t = __shfl_up(inc, o); if (lane >= o) inc += t; }
    if (lane == 63) wtot[wid] = inc;
    __syncthreads();
    if (tid == 0) {
        int run = 0;
        #pragma unroll
        for (int w = 0; w < 16; ++w) { int t = wtot[w]; wtot[w] = run; run += t; }
        partial[blockIdx.x] = run;
    }
    __syncthreads();
    int excl = wtot[wid] + inc - s;
    #pragma unroll
    for (int j = 0; j < 8; ++j) {
        int i = base + j;
        if (i < len) data[i] = excl;
        excl += v[j];
    }
}

__global__ void scan_partials_kernel(int* partial, int nb) {
    int t = threadIdx.x;  // 64 threads; nb <= 128
    int i0 = 2 * t, i1 = 2 * t + 1;
    int v0 = (i0 < nb) ? partial[i0] : 0;
    int v1 = (i1 < nb) ? partial[i1] : 0;
    int s = v0 + v1;
    int inc = s;
    #pragma unroll
    for (int o = 1; o < 64; o <<= 1) { int u = __shfl_up(inc, o); if (t >= o) inc += u; }
    int excl = inc - s;
    if (i0 < nb) partial[i0] = excl;
    if (i1 < nb) partial[i1] = excl + v0;
}

__global__ void add_base_kernel(int* data, const int* __restrict__ partial, int len) {
    int i = blockIdx.x * blockDim.x + threadIdx.x;
    if (i < len) data[i] += partial[i >> 13];
}

// ---------------- pass 2: tile-sort scatter into bucket-ordered ebuf ----------------
// payload packed: (dst & 127) << 17 | src   (src < 2^17)

__global__ void scatter_kernel(const int* __restrict__ src, const int* __restrict__ dst,
                               const int* __restrict__ offset, int* __restrict__ ebuf,
                               int E, int HBr, int nbkt) {
    __shared__ int gbase[NBKT_MAX];
    __shared__ int thist[NBKT_MAX];
    __shared__ int toff[NBKT_MAX + 1];
    __shared__ int stage[CHUNK];
    __shared__ unsigned short bstage[CHUNK];
    __shared__ int wtot4[4];
    int tid = threadIdx.x, lane = tid & 63, wid = tid >> 6;
    for (int i = tid; i < nbkt; i += 256) gbase[i] = offset[(size_t)i * HBr + blockIdx.x];
    for (int i = tid; i < NBKT_MAX; i += 256) thist[i] = 0;
    __syncthreads();
    int start = blockIdx.x * CHUNK;
    int s_[16], d_[16], r_[16];
    #pragma unroll
    for (int j = 0; j < 16; ++j) {
        int e = start + j * 256 + tid;
        if (e < E) {
            s_[j] = src[e];
            d_[j] = dst[e];
            r_[j] = atomicAdd(&thist[d_[j] >> NPB_SHIFT], 1);
        } else {
            d_[j] = -1;
        }
    }
    __syncthreads();
    int a0 = thist[4 * tid], a1 = thist[4 * tid + 1],
        a2 = thist[4 * tid + 2], a3 = thist[4 * tid + 3];
    int ss = a0 + a1 + a2 + a3;
    int inc = ss;
    #pragma unroll
    for (int o = 1; o < 64; o <<= 1) { int t = __shfl_up(inc, o); if (lane >= o) inc += t; }
    if (lane == 63) wtot4[wid] = inc;
    __syncthreads();
    int wbase = 0;
    for (int w = 0; w < wid; ++w) wbase += wtot4[w];
    int excl = wbase + inc - ss;
    toff[4 * tid]     = excl;
    toff[4 * tid + 1] = excl + a0;
    toff[4 * tid + 2] = excl + a0 + a1;
    toff[4 * tid + 3] = excl + a0 + a1 + a2;
    if (tid == 255) toff[1024] = excl + ss;  // total valid
    __syncthreads();
    #pragma unroll
    for (int j = 0; j < 16; ++j) {
        if (d_[j] >= 0) {
            int b = d_[j] >> NPB_SHIFT;
            int q = toff[b] + r_[j];
            stage[q]  = ((d_[j] & (NPB - 1)) << 17) | s_[j];
            bstage[q] = (unsigned short)b;
        }
    }
    __syncthreads();
    int total = toff[1024];
    for (int j = tid; j < total; j += 256) {
        int b = bstage[j];
        ebuf[gbase[b] + (j - toff[b])] = stage[j];
    }
}

// ---------------- pass 3: per-bucket CSR build + row_start + dinv ----------------

__global__ void bucket_build_kernel(const int* __restrict__ ebuf, const int* __restrict__ offset,
                                    int* __restrict__ csr_src, int* __restrict__ row_start,
                                    float* __restrict__ dinv, int E, int HBr, int nbkt, int n) {
    __shared__ int cnt[NPB], cur[NPB];
    __shared__ int stage[STAGE_CAP];
    __shared__ int wtot2[2];
    int tid = threadIdx.x;
    int k = blockIdx.x;
    int bb = offset[(size_t)k * HBr];
    int be = (k + 1 < nbkt) ? offset[(size_t)(k + 1) * HBr] : E;
    int bsize = be - bb;
    if (tid < NPB) cnt[tid] = 0;
    __syncthreads();
    for (int e = bb + tid; e < be; e += 256) atomicAdd(&cnt[ebuf[e] >> 17], 1);
    __syncthreads();
    int lane = tid & 63, wid = tid >> 6;
    int c = 0, inc = 0;
    if (tid < NPB) {
        c = cnt[tid];
        inc = c;
        #pragma unroll
        for (int o = 1; o < 64; o <<= 1) { int t = __shfl_up(inc, o); if (lane >= o) inc += t; }
        if (lane == 63) wtot2[wid] = inc;
    }
    __syncthreads();
    if (tid < NPB) {
        int base = (wid == 1) ? wtot2[0] : 0;
        int excl = base + inc - c;
        cur[tid] = excl;
        int node = k * NPB + tid;
        if (node < n) {
            row_start[node] = bb + excl;
            dinv[node] = rsqrtf((float)(c + 1));  // self-loop
        }
    }
    if (k == 0 && tid == 0) row_start[n] = E;
    __syncthreads();
    if (bsize <= STAGE_CAP) {
        for (int e = bb + tid; e < be; e += 256) {
            int v = ebuf[e];
            int r = atomicAdd(&cur[v >> 17], 1);
            stage[r] = v & 0x1FFFF;
        }
        __syncthreads();
        for (int j = tid; j < bsize; j += 256) csr_src[bb + j] = stage[j];  // coalesced
    } else {
        for (int e = bb + tid; e < be; e += 256) {
            int v = ebuf[e];
            int r = atomicAdd(&cur[v >> 17], 1);
            csr_src[bb + r] = v & 0x1FFFF;
        }
    }
}

// ---------------- pad + scale: g0[i][k] = (k<11) ? x[i][k]*dinv[i] : 0  (16-wide) ------------

__global__ void pad_scale_kernel(const float* __restrict__ x, const float* __restrict__ dinv,
                                 float* __restrict__ g, int n) {
    int i = blockIdx.x * blockDim.x + threadIdx.x;
    if (i >= n) return;
    float s = dinv[i];
    float v[16];
    #pragma unroll
    for (int k = 0; k < 11; ++k) v[k] = x[i * 11 + k] * s;
    #pragma unroll
    for (int k = 11; k < 16; ++k) v[k] = 0.f;
    #pragma unroll
    for (int k = 0; k < 16; ++k) g[i * 16 + k] = v[k];
}

// ---------------- gather-aggregate (unfused; minimal cross-lane traffic) ----------------
// pre[d] = dinv[d] * (sum_{s in N(d)} g[s] + g[d]);  g rows carry dinv[s].
// One wave per node. lane = grp*FOUT + f: each row read is a fully-coalesced
// FOUT*4-byte segment; 32 rows per iteration (coalesced index load + clamp/mask,
// no serial tail); reduce = log2(64/FOUT) shfl_xor stages only (1 or 2).

template <int FOUT>
__global__ void aggregate_kernel(const float* __restrict__ g,
                                 const int* __restrict__ row_start,
                                 const int* __restrict__ csr_src,
                                 const float* __restrict__ dinv,
                                 float* __restrict__ pre, int n) {
    constexpr int NPG   = 64 / FOUT;   // rows per load instruction (2 or 4)
    constexpr int INSTS = 32 / NPG;    // load instructions per 32-row iteration
    int lane = threadIdx.x & 63;
    int wid  = threadIdx.x >> 6;
    int node = blockIdx.x * (blockDim.x >> 6) + wid;
    if (node >= n) return;
    int f   = lane & (FOUT - 1);
    int grp = lane / FOUT;
    int beg = row_start[node];
    int end = row_start[node + 1];
    float acc = 0.f;

    for (int p = beg; p < end; p += 32) {
        int nrem = end - p;                               // wave-uniform
        int idx  = csr_src[min(p + (lane & 31), end - 1)];// coalesced, in-bounds
        int   s[INSTS];
        float m[INSTS];
        #pragma unroll
        for (int u = 0; u < INSTS; ++u) {
            int slot = u * NPG + grp;                     // row slot 0..31
            bool val = slot < nrem;
            int  raw = __shfl(idx, slot);
            s[u] = val ? raw : node;                      // clamp to self row (L1-hot)
            m[u] = val ? 1.f : 0.f;
        }
        float v[INSTS];
        #pragma unroll
        for (int u = 0; u < INSTS; ++u) v[u] = g[(size_t)s[u] * FOUT + f];
        #pragma unroll
        for (int u = 0; u < INSTS; ++u) acc = fmaf(m[u], v[u], acc);
    }

    // reduce across row groups: 1 stage (FOUT=32) or 2 stages (FOUT=16)
    #pragma unroll
    for (int off = FOUT; off < 64; off <<= 1) acc += __shfl_xor(acc, off);

    float val = dinv[node] * (acc + g[(size_t)node * FOUT + f]);
    if (lane < FOUT) pre[(size_t)node * FOUT + f] = val;
}

// ---------------- post-agg linear (thread-per-node): out = [relu](pre @ W + b) [* dinv] -----
// W is FINR x FOUT row-major; LDS-padded to FINP x FOUT (pad rows zeroed).

template <int FINP, int FINR, int FOUT, bool RELU, bool SCALE>
__global__ void linear_kernel(const float* __restrict__ pre, const float* __restrict__ W,
                              const float* __restrict__ bias, const float* __restrict__ dinv,
                              float* __restrict__ out, int n) {
    __shared__ float sW[FINP * FOUT];
    __shared__ float sB[FOUT];
    for (int i = threadIdx.x; i < FINP * FOUT; i += blockDim.x)
        sW[i] = (i < FINR * FOUT) ? W[i] : 0.f;
    for (int i = threadIdx.x; i < FOUT; i += blockDim.x) sB[i] = bias[i];
    __syncthreads();
    int node = blockIdx.x * blockDim.x + threadIdx.x;
    if (node >= n) return;
    float xi[FINP];
    #pragma unroll
    for (int k = 0; k < FINP; ++k) xi[k] = pre[(size_t)node * FINP + k];
    float s = SCALE ? dinv[node] : 1.f;
    #pragma unroll
    for (int fo = 0; fo < FOUT; ++fo) {
        float acc = sB[fo];
        #pragma unroll
        for (int k = 0; k < FINP; ++k) acc = fmaf(xi[k], sW[k * FOUT + fo], acc);
        if (RELU) acc = fmaxf(acc, 0.f);
        out[(size_t)node * FOUT + fo] = acc * s;
    }
}

// ---------------- launch ----------------

extern "C" void kernel_launch(void* const* d_in, const int* in_sizes, int n_in,
                              void* d_out, int out_size, void* d_ws, size_t ws_size,
                              hipStream_t stream) {
    const float* x  = (const float*)d_in[0];
    const int*   ei = (const int*)d_in[1];
    const float* W1 = (const float*)d_in[2];
    const float* b1 = (const float*)d_in[3];
    const float* W2 = (const float*)d_in[4];
    const float* b2 = (const float*)d_in[5];
    const float* W3 = (const float*)d_in[6];
    const float* b3 = (const float*)d_in[7];
    float* out = (float*)d_out;

    const int n = in_sizes[0] / 11;   // 100000
    const int E = in_sizes[1] / 2;    // 3200000
    const int* src = ei;
    const int* dst = ei + E;

    const int nbkt = (n + NPB - 1) >> NPB_SHIFT;        // 782
    const int HBr  = (E + CHUNK - 1) / CHUNK;           // 782
    const size_t len = (size_t)nbkt * HBr;              // 611,524
    const int nb = (int)((len + 8191) / 8192);          // 75 (<=128)

    char* ws = (char*)d_ws;
    size_t off = 0;
    auto alloc = [&](size_t bytes) {
        void* p = ws + off;
        off = (off + bytes + 255) & ~(size_t)255;
        return p;
    };
    int*   offbuf    = (int*)  alloc(len * 4);
    int*   partial   = (int*)  alloc((size_t)128 * 4);
    int*   ebuf      = (int*)  alloc((size_t)E * 4);
    int*   csr_src   = (int*)  alloc((size_t)E * 4);
    int*   row_start = (int*)  alloc((size_t)(n + 1) * 4);
    float* dinv      = (float*)alloc((size_t)n * 4);
    float* g0        = (float*)alloc((size_t)n * 16 * 4);
    float* g1        = (float*)alloc((size_t)n * 16 * 4);
    float* preS      = (float*)alloc((size_t)n * 16 * 4);  // pre1 / pre2
    float* g2        = (float*)alloc((size_t)n * 32 * 4);
    float* preL      = (float*)alloc((size_t)n * 32 * 4);  // pre3
    (void)ws_size;

    const int B = 256;
    int gn   = (n + B - 1) / B;
    int glen = (int)((len + B - 1) / B);
    int gagg = (n + 3) / 4;           // one wave per node

    // ---- atomic-free CSR build ----
    hist_kernel<<<HBr, B, 0, stream>>>(dst, offbuf, E, HBr, nbkt);
    scan_block8_kernel<<<nb, 1024, 0, stream>>>(offbuf, partial, (int)len);
    scan_partials_kernel<<<1, 64, 0, stream>>>(partial, nb);
    add_base_kernel<<<glen, B, 0, stream>>>(offbuf, partial, (int)len);
    scatter_kernel<<<HBr, B, 0, stream>>>(src, dst, offbuf, ebuf, E, HBr, nbkt);
    bucket_build_kernel<<<nbkt, B, 0, stream>>>(ebuf, offbuf, csr_src, row_start, dinv, E, HBr, nbkt, n);

    // ---- g0 = pad16(x) * dinv ----
    pad_scale_kernel<<<gn, B, 0, stream>>>(x, dinv, g0, n);

    // layer 1: agg(16-wide, 11 real) -> linear 11->16, relu, scale
    aggregate_kernel<16><<<gagg, B, 0, stream>>>(g0, row_start, csr_src, dinv, preS, n);
    linear_kernel<16, 11, 16, true, true><<<gn, B, 0, stream>>>(preS, W1, b1, dinv, g1, n);

    // layer 2: agg(16) -> linear 16->32, relu, scale
    aggregate_kernel<16><<<gagg, B, 0, stream>>>(g1, row_start, csr_src, dinv, preS, n);
    linear_kernel<16, 16, 32, true, true><<<gn, B, 0, stream>>>(preS, W2, b2, dinv, g2, n);

    // layer 3: agg(32) -> linear 32->64, no relu, no scale
    aggregate_kernel<32><<<gagg, B, 0, stream>>>(g2, row_start, csr_src, dinv, preL, n);
    linear_kernel<32, 32, 64, false, false><<<gn, B, 0, stream>>>(preL, W3, b3, dinv, out, n);
}